// Round 6
// baseline (381.837 us; speedup 1.0000x reference)
//
#include <hip/hip_runtime.h>
#include <stdint.h>

// Problem constants
#define BB 8
#define TT 4096
#define HH 1024
#define SS 64
#define NHH 16
#define DHH 64

typedef __attribute__((ext_vector_type(8))) short short8;
typedef __attribute__((ext_vector_type(8))) unsigned short ushortx8;
typedef __attribute__((ext_vector_type(4))) float f32x4;
typedef unsigned short u16;

#define GLOAD16(gp, lp)                                                   \
  __builtin_amdgcn_global_load_lds(                                      \
      (const __attribute__((address_space(1))) void*)(gp),               \
      (__attribute__((address_space(3))) void*)(lp), 16, 0, 0)

// counted waitcnt + scheduler fence (rule #18: sched_barrier after inline waitcnt)
#define WAITVM(n)                                                         \
  asm volatile("s_waitcnt vmcnt(" #n ")" ::: "memory");                  \
  __builtin_amdgcn_sched_barrier(0)

__device__ __forceinline__ u16 f2bf(float f) {
  union { float f; uint32_t u; } v;
  v.f = f;
  uint32_t u = v.u;
  uint32_t r = u + 0x7fffu + ((u >> 16) & 1u);
  return (u16)(r >> 16);
}

__device__ __forceinline__ float bf2f(u16 b) {
  union { uint32_t u; float f; } v;
  v.u = ((uint32_t)b) << 16;
  return v.f;
}

// Stage a 128-row x 64-col f32 tile (row stride ld) into swizzled bf16 LDS.
// LDS layout: row*64 + (slot ^ (row&7))*8, slot = k/8 (8 slots of 8 bf16 = 16B).
__device__ __forceinline__ void stage_tile(u16* lds, const float* src, int ld, int tid) {
#pragma unroll
  for (int q = 0; q < 4; ++q) {
    int slot_id = tid + (q << 8);
    int row = slot_id >> 3;
    int sl = slot_id & 7;
    const float* p = src + (size_t)row * ld + (sl << 3);
    float4 x0 = *(const float4*)(p);
    float4 x1 = *(const float4*)(p + 4);
    ushortx8 o;
    o[0] = f2bf(x0.x); o[1] = f2bf(x0.y); o[2] = f2bf(x0.z); o[3] = f2bf(x0.w);
    o[4] = f2bf(x1.x); o[5] = f2bf(x1.y); o[6] = f2bf(x1.z); o[7] = f2bf(x1.w);
    *(ushortx8*)(&lds[(row << 6) + (((sl ^ (row & 7)) << 3))]) = o;
  }
}

// ---------------- conv: f32 matrix -> tiled pre-swizzled bf16 ----------------
__global__ __launch_bounds__(256) void conv_tile_kernel(const float* __restrict__ src,
                                                        int ld, int ntile_k,
                                                        u16* __restrict__ dst) {
  int bid = blockIdx.x;
  int rt = bid / ntile_k;        // row-tile (128 rows)
  int kt = bid - rt * ntile_k;   // k-tile (64 cols)
  const float* s0 = src + (size_t)rt * 128 * ld + kt * 64;
  u16* d0 = dst + (size_t)bid * 8192;
  int tid = threadIdx.x;
#pragma unroll
  for (int q = 0; q < 4; ++q) {
    int slot_id = tid + (q << 8);
    int row = slot_id >> 3;
    int sl = slot_id & 7;
    const float* p = s0 + (size_t)row * ld + (sl << 3);
    float4 x0 = *(const float4*)(p);
    float4 x1 = *(const float4*)(p + 4);
    ushortx8 o;
    o[0] = f2bf(x0.x); o[1] = f2bf(x0.y); o[2] = f2bf(x0.z); o[3] = f2bf(x0.w);
    o[4] = f2bf(x1.x); o[5] = f2bf(x1.y); o[6] = f2bf(x1.z); o[7] = f2bf(x1.w);
    *(ushortx8*)(&d0[(row << 6) + (((sl ^ (row & 7)) << 3))]) = o;
  }
}

// ---------------- K1: sentence mean pooling from tiled bf16 hbf ----------------
__global__ __launch_bounds__(256) void pool_bf_kernel(const u16* __restrict__ hbf,
                                                      const int* __restrict__ bounds,
                                                      float* __restrict__ sent) {
  int bs = blockIdx.x;           // b*64 + s
  int b = bs >> 6;
  int start = bounds[bs * 2];
  int end = bounds[bs * 2 + 1];
  int lo = max(start, 0), hi = min(end, TT);
  int cnt = max(hi - lo, 0);
  float inv = 1.0f / (float)max(cnt, 1);
  int tid = threadIdx.x;
  int sg = tid >> 1;             // 0..127 -> cols sg*8 .. sg*8+7
  int half = tid & 1;
  int kt = sg >> 3, slot = sg & 7;
  float a[8] = {};
  for (int t = lo + half; t < hi; t += 2) {
    int grow = b * TT + t;
    int rt = grow >> 7, r = grow & 127;
    const u16* tile = hbf + ((size_t)rt * 16 + kt) * 8192;
    ushortx8 v = *(const ushortx8*)(&tile[(r << 6) + ((slot ^ (r & 7)) << 3)]);
#pragma unroll
    for (int j = 0; j < 8; ++j) a[j] += bf2f(v[j]);
  }
#pragma unroll
  for (int j = 0; j < 8; ++j) a[j] += __shfl_xor(a[j], 1);
  if (half == 0) {
    float* d = sent + (size_t)bs * HH + sg * 8;
#pragma unroll
    for (int j = 0; j < 8; ++j) d[j] = a[j] * inv;
  }
}

// ---------------- setup: bias-init qkv/att/cbuf + sid, one grid-stride kernel ----------------
__global__ __launch_bounds__(256) void setup_misc(const float* __restrict__ ipb,
                                                  const float* __restrict__ outb,
                                                  const float* __restrict__ b1,
                                                  const int* __restrict__ bounds,
                                                  float* __restrict__ qkv,
                                                  float* __restrict__ att,
                                                  float* __restrict__ cbuf,
                                                  int* __restrict__ sid) {
  int idx = blockIdx.x * 256 + threadIdx.x;
  const int STR = 2048 * 256;
  for (int i = idx; i < 512 * 3072; i += STR) qkv[i] = ipb[i % 3072];
  for (int i = idx; i < 512 * 1024; i += STR) att[i] = outb[i & 1023];
  for (int i = idx; i < 512 * 1024; i += STR) cbuf[i] = b1[i & 1023];
  if (idx < BB * TT) {
    int b = idx >> 12, t = idx & (TT - 1);
    int r = -1;
    for (int s = 0; s < SS; ++s) {
      int st = bounds[(b * SS + s) * 2], en = bounds[(b * SS + s) * 2 + 1];
      if (t >= st && t < en) { r = s; break; }
    }
    sid[idx] = r;
  }
}

// ---------------- C += A @ B^T via atomics, K-split over blockIdx.z ----------------
__global__ __launch_bounds__(256) void gemm_bt_atomic(const float* __restrict__ A, int lda,
                                                      const float* __restrict__ Bm, int ldb,
                                                      float* __restrict__ C, int ldc,
                                                      int kper) {
  __shared__ u16 As[128 * 64];
  __shared__ u16 Bs[128 * 64];
  int tid = threadIdx.x;
  int m0 = blockIdx.x * 128, n0 = blockIdx.y * 128;
  int kbeg = blockIdx.z * kper;
  f32x4 acc[4][4] = {};

  for (int k0 = kbeg; k0 < kbeg + kper; k0 += 64) {
    __syncthreads();
    stage_tile(As, A + (size_t)m0 * lda + k0, lda, tid);
    stage_tile(Bs, Bm + (size_t)n0 * ldb + k0, ldb, tid);
    __syncthreads();
    int lane = tid & 63, wid = tid >> 6;
    int wm = wid >> 1, wn = wid & 1;
    int lr = lane & 15, lg = lane >> 4;
#pragma unroll
    for (int kk = 0; kk < 2; ++kk) {
      short8 af[4], bfr[4];
#pragma unroll
      for (int i = 0; i < 4; ++i) {
        int arow = wm * 64 + i * 16 + lr;
        int aslot = (kk * 4 + lg) ^ (arow & 7);
        af[i] = *(const short8*)(&As[(arow << 6) + (aslot << 3)]);
        int brow = wn * 64 + i * 16 + lr;
        int bslot = (kk * 4 + lg) ^ (brow & 7);
        bfr[i] = *(const short8*)(&Bs[(brow << 6) + (bslot << 3)]);
      }
#pragma unroll
      for (int i = 0; i < 4; ++i)
#pragma unroll
        for (int j = 0; j < 4; ++j)
          acc[i][j] = __builtin_amdgcn_mfma_f32_16x16x32_bf16(af[i], bfr[j], acc[i][j], 0, 0, 0);
    }
  }

  int lane = tid & 63, wid = tid >> 6;
  int wm = wid >> 1, wn = wid & 1;
  int lr = lane & 15, lg = lane >> 4;
#pragma unroll
  for (int i = 0; i < 4; ++i)
#pragma unroll
    for (int j = 0; j < 4; ++j)
#pragma unroll
      for (int r = 0; r < 4; ++r) {
        int row = m0 + wm * 64 + i * 16 + lg * 4 + r;
        int col = n0 + wn * 64 + j * 16 + lr;
        atomicAdd(&C[(size_t)row * ldc + col], acc[i][j][r]);
      }
}

// ---------------- K4: attention over S=64 per (b, head) ----------------
__global__ __launch_bounds__(256) void attn_kernel(const float* __restrict__ qkv,
                                                   float* __restrict__ ctx) {
  int bh = blockIdx.x;
  int b = bh >> 4, nh = bh & 15;
  __shared__ float q[64][64], k[64][64], v[64][64], s[64][64];
  int tid = threadIdx.x;
  const float* base = qkv + (size_t)b * SS * 3072 + nh * 64;
  for (int e = tid; e < 4096; e += 256) {
    int i = e >> 6, d = e & 63;
    q[i][d] = base[(size_t)i * 3072 + d];
    k[i][d] = base[(size_t)i * 3072 + 1024 + d];
    v[i][d] = base[(size_t)i * 3072 + 2048 + d];
  }
  __syncthreads();
  for (int e = tid; e < 4096; e += 256) {
    int i = e >> 6, j = e & 63;
    float acc = 0.f;
#pragma unroll 8
    for (int d = 0; d < 64; ++d) acc += q[i][d] * k[j][d];
    s[i][j] = acc * 0.125f;  // 1/sqrt(64)
  }
  __syncthreads();
  {
    int r = tid >> 2, sub = tid & 3;
    int j0 = sub * 16;
    float m = -1e30f;
#pragma unroll
    for (int j = 0; j < 16; ++j) m = fmaxf(m, s[r][j0 + j]);
    m = fmaxf(m, __shfl_xor(m, 1));
    m = fmaxf(m, __shfl_xor(m, 2));
    float sum = 0.f;
#pragma unroll
    for (int j = 0; j < 16; ++j) {
      float e_ = __expf(s[r][j0 + j] - m);
      s[r][j0 + j] = e_;
      sum += e_;
    }
    sum += __shfl_xor(sum, 1);
    sum += __shfl_xor(sum, 2);
    float inv = 1.0f / sum;
#pragma unroll
    for (int j = 0; j < 16; ++j) s[r][j0 + j] *= inv;
  }
  __syncthreads();
  for (int e = tid; e < 4096; e += 256) {
    int i = e >> 6, d = e & 63;
    float acc = 0.f;
#pragma unroll 8
    for (int j = 0; j < 64; ++j) acc += s[i][j] * v[j][d];
    ctx[((size_t)b * SS + i) * HH + nh * 64 + d] = acc;
  }
}

// ---------------- K7: partial score, quad-buffered counted-vmcnt pipeline ----------------
// XCD-grouped swizzle as round 5. Single raw s_barrier per K-step; staging loads
// for tiles i+1, i+2 stay in flight across it (vmcnt(16), never 0 mid-loop).
// RAW: vmcnt(16) retires tile i's 8 loads per wave, then barrier -> all waves' done.
// WAR: buf[(i+2)&3] was last read at compute(i-2), >= 2 barriers earlier; every
// ds_read is consumed by an MFMA before that wave's next barrier (compiler lgkmcnt).
__global__ __launch_bounds__(256) void score_partial(const u16* __restrict__ hbf,
                                                     const u16* __restrict__ wbf,
                                                     const float* __restrict__ cbuf,
                                                     const float* __restrict__ w2,
                                                     const int* __restrict__ sid_arr,
                                                     float* __restrict__ score_part) {
  __shared__ u16 Abuf[4][8192];
  __shared__ u16 Bbuf[4][8192];
  __shared__ float w2_lds[128];
  __shared__ int sid_lds[128];
  __shared__ float red[128];

  int tid = threadIdx.x;
  int bid = blockIdx.x;
  int x = bid & 7;
  int g = bid >> 3;
  int mt = x * 32 + (g >> 3);
  int c = g & 7;
  int n0 = c * 128;
  size_t g0 = (size_t)mt * 128;  // global token row
  int b = (int)(g0 >> 12);       // / T
  const u16* asrc = hbf + (size_t)mt * 16 * 8192;
  const u16* bsrc = wbf + (size_t)c * 16 * 8192;

  // init first: these 2 global loads retire (compiler waitcnt) before any STAGE
  // is issued, so they never perturb the loop's vmcnt accounting.
  if (tid < 128) {
    w2_lds[tid] = w2[n0 + tid];
    sid_lds[tid] = sid_arr[g0 + tid];
    red[tid] = 0.f;
  }

  int lane = tid & 63, wv = tid >> 6;
  int wm = wv >> 1, wn = wv & 1;
  int lr = lane & 15, lg = lane >> 4;

#define STAGE_KT(kt, bufi)                                                \
  {                                                                       \
    const u16* at_ = asrc + (kt) * 8192;                                  \
    const u16* bt_ = bsrc + (kt) * 8192;                                  \
    _Pragma("unroll")                                                     \
    for (int q = 0; q < 4; ++q) {                                         \
      int off_ = q * 2048 + wv * 512 + lane * 8;                          \
      GLOAD16(at_ + off_, &Abuf[bufi][q * 2048 + wv * 512]);              \
      GLOAD16(bt_ + off_, &Bbuf[bufi][q * 2048 + wv * 512]);              \
    }                                                                     \
  }

  STAGE_KT(0, 0);
  STAGE_KT(1, 1);

  f32x4 acc[4][4] = {};
  for (int i = 0; i < 16; ++i) {
    if (i < 14) {
      STAGE_KT(i + 2, (i + 2) & 3);
      WAITVM(16);        // tiles i+1, i+2 in flight; tile i complete
    } else if (i == 14) {
      WAITVM(8);         // tile 15 in flight; tile 14 complete
    } else {
      WAITVM(0);         // tile 15 complete
    }
    __builtin_amdgcn_s_barrier();
    const u16* As = Abuf[i & 3];
    const u16* Bs = Bbuf[i & 3];
#pragma unroll
    for (int kk = 0; kk < 2; ++kk) {
      short8 af[4], bfr[4];
#pragma unroll
      for (int ii = 0; ii < 4; ++ii) {
        int arow = wm * 64 + ii * 16 + lr;
        int aslot = (kk * 4 + lg) ^ (arow & 7);
        af[ii] = *(const short8*)(&As[(arow << 6) + (aslot << 3)]);
        int brow = wn * 64 + ii * 16 + lr;
        int bslot = (kk * 4 + lg) ^ (brow & 7);
        bfr[ii] = *(const short8*)(&Bs[(brow << 6) + (bslot << 3)]);
      }
#pragma unroll
      for (int ii = 0; ii < 4; ++ii)
#pragma unroll
        for (int j = 0; j < 4; ++j)
          acc[ii][j] = __builtin_amdgcn_mfma_f32_16x16x32_bf16(af[ii], bfr[j], acc[ii][j], 0, 0, 0);
    }
  }
#undef STAGE_KT

  // score epilogue: sp = sum_j w2[j] * relu(u + c[sid, j]) over this chunk's 128 cols
  float sp[4][4];
#pragma unroll
  for (int i = 0; i < 4; ++i) {
#pragma unroll
    for (int r = 0; r < 4; ++r) {
      int rowl = wm * 64 + i * 16 + lg * 4 + r;
      int s = sid_lds[rowl];
      int sc = s < 0 ? 0 : s;
      const float* crow = cbuf + ((size_t)b * SS + sc) * HH + n0;
      float accs = 0.f;
#pragma unroll
      for (int j = 0; j < 4; ++j) {
        int coll = wn * 64 + j * 16 + lr;
        float t = acc[i][j][r] + crow[coll];
        if (t > 0.f) accs += t * w2_lds[coll];
      }
      sp[i][r] = accs;
    }
  }

  // reduce across the 16 lanes of each lane-group
#pragma unroll
  for (int i = 0; i < 4; ++i)
#pragma unroll
    for (int r = 0; r < 4; ++r) {
      float v = sp[i][r];
      v += __shfl_xor(v, 1);
      v += __shfl_xor(v, 2);
      v += __shfl_xor(v, 4);
      v += __shfl_xor(v, 8);
      sp[i][r] = v;
    }
  if (lr == 0) {
#pragma unroll
    for (int i = 0; i < 4; ++i)
#pragma unroll
      for (int r = 0; r < 4; ++r)
        atomicAdd(&red[wm * 64 + i * 16 + lg * 4 + r], sp[i][r]);
  }
  __syncthreads();
  if (tid < 128) score_part[(size_t)c * (BB * TT) + g0 + tid] = red[tid];
}

// ---------------- K9: out = h * (1 + covered*(sum_c spart + b2)) ----------------
__global__ __launch_bounds__(256) void scale_kernel(const float* __restrict__ h,
                                                    const float* __restrict__ score_part,
                                                    const float* __restrict__ b2,
                                                    const int* __restrict__ sid_arr,
                                                    float* __restrict__ out) {
  __shared__ float fac[16];
  int tid = threadIdx.x;
  int r0 = blockIdx.x * 16;
  if (tid < 16) {
    int t = r0 + tid;
    float s = b2[0];
#pragma unroll
    for (int c = 0; c < 8; ++c) s += score_part[(size_t)c * (BB * TT) + t];
    fac[tid] = (sid_arr[t] >= 0) ? (1.0f + s) : 1.0f;
  }
  __syncthreads();
  const float4* h4 = (const float4*)h + (size_t)r0 * 256;
  float4* o4 = (float4*)out + (size_t)r0 * 256;
  for (int e = tid; e < 16 * 256; e += 256) {
    float f = fac[e >> 8];
    float4 v = h4[e];
    v.x *= f; v.y *= f; v.z *= f; v.w *= f;
    o4[e] = v;
  }
}

extern "C" void kernel_launch(void* const* d_in, const int* in_sizes, int n_in,
                              void* d_out, int out_size, void* d_ws, size_t ws_size,
                              hipStream_t stream) {
  const float* h        = (const float*)d_in[0];
  const int*   bounds   = (const int*)d_in[1];
  const float* in_proj_w = (const float*)d_in[2];
  const float* in_proj_b = (const float*)d_in[3];
  const float* out_w    = (const float*)d_in[4];
  const float* out_b    = (const float*)d_in[5];
  const float* w1       = (const float*)d_in[6];
  const float* b1       = (const float*)d_in[7];
  const float* w2       = (const float*)d_in[8];
  const float* b2       = (const float*)d_in[9];
  float* out = (float*)d_out;

  char* ws = (char*)d_ws;
  float* sent  = (float*)(ws);                        // 2 MB
  float* qkv   = (float*)(ws + (2ull << 20));         // 6 MB
  float* ctx   = (float*)(ws + (8ull << 20));         // 2 MB
  float* att   = (float*)(ws + (10ull << 20));        // 2 MB
  float* cbuf  = (float*)(ws + (12ull << 20));        // 2 MB
  int*   sid   = (int*)(ws + (14ull << 20));          // 128 KB
  float* spart = (float*)(ws + (15ull << 20));        // 1 MB
  u16*   hbf   = (u16*)(ws + (16ull << 20));          // 64 MB
  u16*   wbf   = (u16*)(ws + (80ull << 20));          // 2 MB

  // pre-convert operands of the big GEMM to tiled/swizzled bf16
  conv_tile_kernel<<<256 * 16, 256, 0, stream>>>(h, HH, 16, hbf);
  conv_tile_kernel<<<8 * 16, 256, 0, stream>>>(w1, 2 * HH, 16, wbf);  // w1a: k<1024

  pool_bf_kernel<<<BB * SS, 256, 0, stream>>>(hbf, bounds, sent);
  setup_misc<<<2048, 256, 0, stream>>>(in_proj_b, out_b, b1, bounds, qkv, att, cbuf, sid);

  // qkv = sent @ in_proj_w^T + in_proj_b   (512 x 3072, K=1024), K-split x4
  gemm_bt_atomic<<<dim3(4, 24, 4), 256, 0, stream>>>(sent, HH, in_proj_w, HH, qkv, 3 * HH, 256);
  attn_kernel<<<BB * NHH, 256, 0, stream>>>(qkv, ctx);
  // attended = ctx @ out_w^T + out_b       (512 x 1024, K=1024), K-split x4
  gemm_bt_atomic<<<dim3(4, 8, 4), 256, 0, stream>>>(ctx, HH, out_w, HH, att, HH, 256);
  // c = attended @ w1b^T + b1              (512 x 1024, K=1024), w1b = w1[:, H:]
  gemm_bt_atomic<<<dim3(4, 8, 4), 256, 0, stream>>>(att, HH, w1 + HH, 2 * HH, cbuf, HH, 256);

  // big GEMM partial scores: 2048 blocks, XCD-grouped, quad-buffer pipeline
  score_partial<<<2048, 256, 0, stream>>>(hbf, wbf, cbuf, w2, sid, spart);
  scale_kernel<<<2048, 256, 0, stream>>>(h, spart, b2, sid, out);
}

// Round 7
// 332.767 us; speedup vs baseline: 1.1475x; 1.1475x over previous
//
#include <hip/hip_runtime.h>
#include <stdint.h>

// Problem constants
#define BB 8
#define TT 4096
#define HH 1024
#define SS 64
#define NHH 16
#define DHH 64

typedef __attribute__((ext_vector_type(8))) short short8;
typedef __attribute__((ext_vector_type(8))) unsigned short ushortx8;
typedef __attribute__((ext_vector_type(4))) float f32x4;
typedef unsigned short u16;

#define GLOAD16(gp, lp)                                                   \
  __builtin_amdgcn_global_load_lds(                                      \
      (const __attribute__((address_space(1))) void*)(gp),               \
      (__attribute__((address_space(3))) void*)(lp), 16, 0, 0)

__device__ __forceinline__ u16 f2bf(float f) {
  union { float f; uint32_t u; } v;
  v.f = f;
  uint32_t u = v.u;
  uint32_t r = u + 0x7fffu + ((u >> 16) & 1u);
  return (u16)(r >> 16);
}

__device__ __forceinline__ float bf2f(u16 b) {
  union { uint32_t u; float f; } v;
  v.u = ((uint32_t)b) << 16;
  return v.f;
}

// Stage a 128-row x 64-col f32 tile (row stride ld) into swizzled bf16 LDS.
// LDS layout: row*64 + (slot ^ (row&7))*8, slot = k/8 (8 slots of 8 bf16 = 16B).
__device__ __forceinline__ void stage_tile(u16* lds, const float* src, int ld, int tid) {
#pragma unroll
  for (int q = 0; q < 4; ++q) {
    int slot_id = tid + (q << 8);
    int row = slot_id >> 3;
    int sl = slot_id & 7;
    const float* p = src + (size_t)row * ld + (sl << 3);
    float4 x0 = *(const float4*)(p);
    float4 x1 = *(const float4*)(p + 4);
    ushortx8 o;
    o[0] = f2bf(x0.x); o[1] = f2bf(x0.y); o[2] = f2bf(x0.z); o[3] = f2bf(x0.w);
    o[4] = f2bf(x1.x); o[5] = f2bf(x1.y); o[6] = f2bf(x1.z); o[7] = f2bf(x1.w);
    *(ushortx8*)(&lds[(row << 6) + (((sl ^ (row & 7)) << 3))]) = o;
  }
}

// ---------------- conv: f32 matrix -> tiled pre-swizzled bf16 ----------------
__global__ __launch_bounds__(256) void conv_tile_kernel(const float* __restrict__ src,
                                                        int ld, int ntile_k,
                                                        u16* __restrict__ dst) {
  int bid = blockIdx.x;
  int rt = bid / ntile_k;        // row-tile (128 rows)
  int kt = bid - rt * ntile_k;   // k-tile (64 cols)
  const float* s0 = src + (size_t)rt * 128 * ld + kt * 64;
  u16* d0 = dst + (size_t)bid * 8192;
  int tid = threadIdx.x;
#pragma unroll
  for (int q = 0; q < 4; ++q) {
    int slot_id = tid + (q << 8);
    int row = slot_id >> 3;
    int sl = slot_id & 7;
    const float* p = s0 + (size_t)row * ld + (sl << 3);
    float4 x0 = *(const float4*)(p);
    float4 x1 = *(const float4*)(p + 4);
    ushortx8 o;
    o[0] = f2bf(x0.x); o[1] = f2bf(x0.y); o[2] = f2bf(x0.z); o[3] = f2bf(x0.w);
    o[4] = f2bf(x1.x); o[5] = f2bf(x1.y); o[6] = f2bf(x1.z); o[7] = f2bf(x1.w);
    *(ushortx8*)(&d0[(row << 6) + (((sl ^ (row & 7)) << 3))]) = o;
  }
}

// ---------------- K1: sentence mean pooling from tiled bf16 hbf ----------------
__global__ __launch_bounds__(256) void pool_bf_kernel(const u16* __restrict__ hbf,
                                                      const int* __restrict__ bounds,
                                                      float* __restrict__ sent) {
  int bs = blockIdx.x;           // b*64 + s
  int b = bs >> 6;
  int start = bounds[bs * 2];
  int end = bounds[bs * 2 + 1];
  int lo = max(start, 0), hi = min(end, TT);
  int cnt = max(hi - lo, 0);
  float inv = 1.0f / (float)max(cnt, 1);
  int tid = threadIdx.x;
  int sg = tid >> 1;             // 0..127 -> cols sg*8 .. sg*8+7
  int half = tid & 1;
  int kt = sg >> 3, slot = sg & 7;
  float a[8] = {};
  for (int t = lo + half; t < hi; t += 2) {
    int grow = b * TT + t;
    int rt = grow >> 7, r = grow & 127;
    const u16* tile = hbf + ((size_t)rt * 16 + kt) * 8192;
    ushortx8 v = *(const ushortx8*)(&tile[(r << 6) + ((slot ^ (r & 7)) << 3)]);
#pragma unroll
    for (int j = 0; j < 8; ++j) a[j] += bf2f(v[j]);
  }
#pragma unroll
  for (int j = 0; j < 8; ++j) a[j] += __shfl_xor(a[j], 1);
  if (half == 0) {
    float* d = sent + (size_t)bs * HH + sg * 8;
#pragma unroll
    for (int j = 0; j < 8; ++j) d[j] = a[j] * inv;
  }
}

// ---------------- setup: bias-init qkv/att/cbuf + sid, one grid-stride kernel ----------------
__global__ __launch_bounds__(256) void setup_misc(const float* __restrict__ ipb,
                                                  const float* __restrict__ outb,
                                                  const float* __restrict__ b1,
                                                  const int* __restrict__ bounds,
                                                  float* __restrict__ qkv,
                                                  float* __restrict__ att,
                                                  float* __restrict__ cbuf,
                                                  int* __restrict__ sid) {
  int idx = blockIdx.x * 256 + threadIdx.x;
  const int STR = 2048 * 256;
  for (int i = idx; i < 512 * 3072; i += STR) qkv[i] = ipb[i % 3072];
  for (int i = idx; i < 512 * 1024; i += STR) att[i] = outb[i & 1023];
  for (int i = idx; i < 512 * 1024; i += STR) cbuf[i] = b1[i & 1023];
  if (idx < BB * TT) {
    int b = idx >> 12, t = idx & (TT - 1);
    int r = -1;
    for (int s = 0; s < SS; ++s) {
      int st = bounds[(b * SS + s) * 2], en = bounds[(b * SS + s) * 2 + 1];
      if (t >= st && t < en) { r = s; break; }
    }
    sid[idx] = r;
  }
}

// ---------------- C += A @ B^T via atomics, K-split over blockIdx.z ----------------
__global__ __launch_bounds__(256) void gemm_bt_atomic(const float* __restrict__ A, int lda,
                                                      const float* __restrict__ Bm, int ldb,
                                                      float* __restrict__ C, int ldc,
                                                      int kper) {
  __shared__ u16 As[128 * 64];
  __shared__ u16 Bs[128 * 64];
  int tid = threadIdx.x;
  int m0 = blockIdx.x * 128, n0 = blockIdx.y * 128;
  int kbeg = blockIdx.z * kper;
  f32x4 acc[4][4] = {};

  for (int k0 = kbeg; k0 < kbeg + kper; k0 += 64) {
    __syncthreads();
    stage_tile(As, A + (size_t)m0 * lda + k0, lda, tid);
    stage_tile(Bs, Bm + (size_t)n0 * ldb + k0, ldb, tid);
    __syncthreads();
    int lane = tid & 63, wid = tid >> 6;
    int wm = wid >> 1, wn = wid & 1;
    int lr = lane & 15, lg = lane >> 4;
#pragma unroll
    for (int kk = 0; kk < 2; ++kk) {
      short8 af[4], bfr[4];
#pragma unroll
      for (int i = 0; i < 4; ++i) {
        int arow = wm * 64 + i * 16 + lr;
        int aslot = (kk * 4 + lg) ^ (arow & 7);
        af[i] = *(const short8*)(&As[(arow << 6) + (aslot << 3)]);
        int brow = wn * 64 + i * 16 + lr;
        int bslot = (kk * 4 + lg) ^ (brow & 7);
        bfr[i] = *(const short8*)(&Bs[(brow << 6) + (bslot << 3)]);
      }
#pragma unroll
      for (int i = 0; i < 4; ++i)
#pragma unroll
        for (int j = 0; j < 4; ++j)
          acc[i][j] = __builtin_amdgcn_mfma_f32_16x16x32_bf16(af[i], bfr[j], acc[i][j], 0, 0, 0);
    }
  }

  int lane = tid & 63, wid = tid >> 6;
  int wm = wid >> 1, wn = wid & 1;
  int lr = lane & 15, lg = lane >> 4;
#pragma unroll
  for (int i = 0; i < 4; ++i)
#pragma unroll
    for (int j = 0; j < 4; ++j)
#pragma unroll
      for (int r = 0; r < 4; ++r) {
        int row = m0 + wm * 64 + i * 16 + lg * 4 + r;
        int col = n0 + wn * 64 + j * 16 + lr;
        atomicAdd(&C[(size_t)row * ldc + col], acc[i][j][r]);
      }
}

// ---------------- K4: attention over S=64 per (b, head) ----------------
__global__ __launch_bounds__(256) void attn_kernel(const float* __restrict__ qkv,
                                                   float* __restrict__ ctx) {
  int bh = blockIdx.x;
  int b = bh >> 4, nh = bh & 15;
  __shared__ float q[64][64], k[64][64], v[64][64], s[64][64];
  int tid = threadIdx.x;
  const float* base = qkv + (size_t)b * SS * 3072 + nh * 64;
  for (int e = tid; e < 4096; e += 256) {
    int i = e >> 6, d = e & 63;
    q[i][d] = base[(size_t)i * 3072 + d];
    k[i][d] = base[(size_t)i * 3072 + 1024 + d];
    v[i][d] = base[(size_t)i * 3072 + 2048 + d];
  }
  __syncthreads();
  for (int e = tid; e < 4096; e += 256) {
    int i = e >> 6, j = e & 63;
    float acc = 0.f;
#pragma unroll 8
    for (int d = 0; d < 64; ++d) acc += q[i][d] * k[j][d];
    s[i][j] = acc * 0.125f;  // 1/sqrt(64)
  }
  __syncthreads();
  {
    int r = tid >> 2, sub = tid & 3;
    int j0 = sub * 16;
    float m = -1e30f;
#pragma unroll
    for (int j = 0; j < 16; ++j) m = fmaxf(m, s[r][j0 + j]);
    m = fmaxf(m, __shfl_xor(m, 1));
    m = fmaxf(m, __shfl_xor(m, 2));
    float sum = 0.f;
#pragma unroll
    for (int j = 0; j < 16; ++j) {
      float e_ = __expf(s[r][j0 + j] - m);
      s[r][j0 + j] = e_;
      sum += e_;
    }
    sum += __shfl_xor(sum, 1);
    sum += __shfl_xor(sum, 2);
    float inv = 1.0f / sum;
#pragma unroll
    for (int j = 0; j < 16; ++j) s[r][j0 + j] *= inv;
  }
  __syncthreads();
  for (int e = tid; e < 4096; e += 256) {
    int i = e >> 6, d = e & 63;
    float acc = 0.f;
#pragma unroll 8
    for (int j = 0; j < 64; ++j) acc += s[i][j] * v[j][d];
    ctx[((size_t)b * SS + i) * HH + nh * 64 + d] = acc;
  }
}

// ---------------- K7: partial score, 2-phase double-buffer ----------------
// XCD-grouped swizzle as round 5. Per K-step: STAGE(next tile -> other buf) is
// ISSUED first, then compute(cur buf) runs while those loads fly, then one
// vmcnt(0) + barrier retires them. One barrier per step (vs 2 in round 5).
// RAW: tile i's loads drained by iter i-1's vmcnt(0)+barrier. WAR: STAGE at
// iter i writes the buffer whose reads were consumed (lgkmcnt before MFMA)
// before the iter i-1 barrier. LDS 2x32KB+1.2KB -> 2 blocks/CU preserved.
__global__ __launch_bounds__(256) void score_partial(const u16* __restrict__ hbf,
                                                     const u16* __restrict__ wbf,
                                                     const float* __restrict__ cbuf,
                                                     const float* __restrict__ w2,
                                                     const int* __restrict__ sid_arr,
                                                     float* __restrict__ score_part) {
  __shared__ u16 Abuf0[8192], Abuf1[8192];
  __shared__ u16 Bbuf0[8192], Bbuf1[8192];
  __shared__ float w2_lds[128];
  __shared__ int sid_lds[128];
  __shared__ float red[128];

  int tid = threadIdx.x;
  int bid = blockIdx.x;
  int x = bid & 7;
  int g = bid >> 3;
  int mt = x * 32 + (g >> 3);
  int c = g & 7;
  int n0 = c * 128;
  size_t g0 = (size_t)mt * 128;  // global token row
  int b = (int)(g0 >> 12);       // / T
  const u16* asrc = hbf + (size_t)mt * 16 * 8192;
  const u16* bsrc = wbf + (size_t)c * 16 * 8192;

  if (tid < 128) {
    w2_lds[tid] = w2[n0 + tid];
    sid_lds[tid] = sid_arr[g0 + tid];
    red[tid] = 0.f;
  }

  int lane = tid & 63, wv = tid >> 6;
  int wm = wv >> 1, wn = wv & 1;
  int lr = lane & 15, lg = lane >> 4;

#define STAGE_KT(kt, dA, dB)                                              \
  {                                                                       \
    const u16* at_ = asrc + (kt) * 8192;                                  \
    const u16* bt_ = bsrc + (kt) * 8192;                                  \
    _Pragma("unroll")                                                     \
    for (int q = 0; q < 4; ++q) {                                         \
      int off_ = q * 2048 + wv * 512 + lane * 8;                          \
      GLOAD16(at_ + off_, (dA) + q * 2048 + wv * 512);                    \
      GLOAD16(bt_ + off_, (dB) + q * 2048 + wv * 512);                    \
    }                                                                     \
  }

#define STEP_SYNC()                                                       \
  asm volatile("s_waitcnt vmcnt(0)" ::: "memory");                       \
  __builtin_amdgcn_sched_barrier(0);                                     \
  __builtin_amdgcn_s_barrier();                                          \
  __builtin_amdgcn_sched_barrier(0)

  u16* curA = Abuf0; u16* nxtA = Abuf1;
  u16* curB = Bbuf0; u16* nxtB = Bbuf1;

  STAGE_KT(0, curA, curB);
  STEP_SYNC();

  f32x4 acc[4][4] = {};
  for (int i = 0; i < 16; ++i) {
    if (i < 15) STAGE_KT(i + 1, nxtA, nxtB);
    const u16* As = curA;
    const u16* Bs = curB;
#pragma unroll
    for (int kk = 0; kk < 2; ++kk) {
      short8 af[4], bfr[4];
#pragma unroll
      for (int ii = 0; ii < 4; ++ii) {
        int arow = wm * 64 + ii * 16 + lr;
        int aslot = (kk * 4 + lg) ^ (arow & 7);
        af[ii] = *(const short8*)(&As[(arow << 6) + (aslot << 3)]);
        int brow = wn * 64 + ii * 16 + lr;
        int bslot = (kk * 4 + lg) ^ (brow & 7);
        bfr[ii] = *(const short8*)(&Bs[(brow << 6) + (bslot << 3)]);
      }
#pragma unroll
      for (int ii = 0; ii < 4; ++ii)
#pragma unroll
        for (int j = 0; j < 4; ++j)
          acc[ii][j] = __builtin_amdgcn_mfma_f32_16x16x32_bf16(af[ii], bfr[j], acc[ii][j], 0, 0, 0);
    }
    STEP_SYNC();
    u16* tA = curA; curA = nxtA; nxtA = tA;
    u16* tB = curB; curB = nxtB; nxtB = tB;
  }
#undef STAGE_KT
#undef STEP_SYNC

  // score epilogue: sp = sum_j w2[j] * relu(u + c[sid, j]) over this chunk's 128 cols
  float sp[4][4];
#pragma unroll
  for (int i = 0; i < 4; ++i) {
#pragma unroll
    for (int r = 0; r < 4; ++r) {
      int rowl = wm * 64 + i * 16 + lg * 4 + r;
      int s = sid_lds[rowl];
      int sc = s < 0 ? 0 : s;
      const float* crow = cbuf + ((size_t)b * SS + sc) * HH + n0;
      float accs = 0.f;
#pragma unroll
      for (int j = 0; j < 4; ++j) {
        int coll = wn * 64 + j * 16 + lr;
        float t = acc[i][j][r] + crow[coll];
        if (t > 0.f) accs += t * w2_lds[coll];
      }
      sp[i][r] = accs;
    }
  }

  // reduce across the 16 lanes of each lane-group
#pragma unroll
  for (int i = 0; i < 4; ++i)
#pragma unroll
    for (int r = 0; r < 4; ++r) {
      float v = sp[i][r];
      v += __shfl_xor(v, 1);
      v += __shfl_xor(v, 2);
      v += __shfl_xor(v, 4);
      v += __shfl_xor(v, 8);
      sp[i][r] = v;
    }
  if (lr == 0) {
#pragma unroll
    for (int i = 0; i < 4; ++i)
#pragma unroll
      for (int r = 0; r < 4; ++r)
        atomicAdd(&red[wm * 64 + i * 16 + lg * 4 + r], sp[i][r]);
  }
  __syncthreads();
  if (tid < 128) score_part[(size_t)c * (BB * TT) + g0 + tid] = red[tid];
}

// ---------------- K9: out = h * (1 + covered*(sum_c spart + b2)) ----------------
__global__ __launch_bounds__(256) void scale_kernel(const float* __restrict__ h,
                                                    const float* __restrict__ score_part,
                                                    const float* __restrict__ b2,
                                                    const int* __restrict__ sid_arr,
                                                    float* __restrict__ out) {
  __shared__ float fac[16];
  int tid = threadIdx.x;
  int r0 = blockIdx.x * 16;
  if (tid < 16) {
    int t = r0 + tid;
    float s = b2[0];
#pragma unroll
    for (int c = 0; c < 8; ++c) s += score_part[(size_t)c * (BB * TT) + t];
    fac[tid] = (sid_arr[t] >= 0) ? (1.0f + s) : 1.0f;
  }
  __syncthreads();
  const float4* h4 = (const float4*)h + (size_t)r0 * 256;
  float4* o4 = (float4*)out + (size_t)r0 * 256;
  for (int e = tid; e < 16 * 256; e += 256) {
    float f = fac[e >> 8];
    float4 v = h4[e];
    v.x *= f; v.y *= f; v.z *= f; v.w *= f;
    o4[e] = v;
  }
}

extern "C" void kernel_launch(void* const* d_in, const int* in_sizes, int n_in,
                              void* d_out, int out_size, void* d_ws, size_t ws_size,
                              hipStream_t stream) {
  const float* h        = (const float*)d_in[0];
  const int*   bounds   = (const int*)d_in[1];
  const float* in_proj_w = (const float*)d_in[2];
  const float* in_proj_b = (const float*)d_in[3];
  const float* out_w    = (const float*)d_in[4];
  const float* out_b    = (const float*)d_in[5];
  const float* w1       = (const float*)d_in[6];
  const float* b1       = (const float*)d_in[7];
  const float* w2       = (const float*)d_in[8];
  const float* b2       = (const float*)d_in[9];
  float* out = (float*)d_out;

  char* ws = (char*)d_ws;
  float* sent  = (float*)(ws);                        // 2 MB
  float* qkv   = (float*)(ws + (2ull << 20));         // 6 MB
  float* ctx   = (float*)(ws + (8ull << 20));         // 2 MB
  float* att   = (float*)(ws + (10ull << 20));        // 2 MB
  float* cbuf  = (float*)(ws + (12ull << 20));        // 2 MB
  int*   sid   = (int*)(ws + (14ull << 20));          // 128 KB
  float* spart = (float*)(ws + (15ull << 20));        // 1 MB
  u16*   hbf   = (u16*)(ws + (16ull << 20));          // 64 MB
  u16*   wbf   = (u16*)(ws + (80ull << 20));          // 2 MB

  // pre-convert operands of the big GEMM to tiled/swizzled bf16
  conv_tile_kernel<<<256 * 16, 256, 0, stream>>>(h, HH, 16, hbf);
  conv_tile_kernel<<<8 * 16, 256, 0, stream>>>(w1, 2 * HH, 16, wbf);  // w1a: k<1024

  pool_bf_kernel<<<BB * SS, 256, 0, stream>>>(hbf, bounds, sent);
  setup_misc<<<2048, 256, 0, stream>>>(in_proj_b, out_b, b1, bounds, qkv, att, cbuf, sid);

  // qkv = sent @ in_proj_w^T + in_proj_b   (512 x 3072, K=1024), K-split x4
  gemm_bt_atomic<<<dim3(4, 24, 4), 256, 0, stream>>>(sent, HH, in_proj_w, HH, qkv, 3 * HH, 256);
  attn_kernel<<<BB * NHH, 256, 0, stream>>>(qkv, ctx);
  // attended = ctx @ out_w^T + out_b       (512 x 1024, K=1024), K-split x4
  gemm_bt_atomic<<<dim3(4, 8, 4), 256, 0, stream>>>(ctx, HH, out_w, HH, att, HH, 256);
  // c = attended @ w1b^T + b1              (512 x 1024, K=1024), w1b = w1[:, H:]
  gemm_bt_atomic<<<dim3(4, 8, 4), 256, 0, stream>>>(att, HH, w1 + HH, 2 * HH, cbuf, HH, 256);

  // big GEMM partial scores: 2048 blocks, XCD-grouped, 2-phase double-buffer
  score_partial<<<2048, 256, 0, stream>>>(hbf, wbf, cbuf, w2, sid, spart);
  scale_kernel<<<2048, 256, 0, stream>>>(h, spart, b2, sid, out);
}

// Round 8
// 300.402 us; speedup vs baseline: 1.2711x; 1.1077x over previous
//
#include <hip/hip_runtime.h>
#include <stdint.h>

// Problem constants
#define BB 8
#define TT 4096
#define HH 1024
#define SS 64
#define NHH 16
#define DHH 64

typedef __attribute__((ext_vector_type(8))) short short8;
typedef __attribute__((ext_vector_type(8))) unsigned short ushortx8;
typedef __attribute__((ext_vector_type(4))) float f32x4;
typedef unsigned short u16;

#define GLOAD16(gp, lp)                                                   \
  __builtin_amdgcn_global_load_lds(                                      \
      (const __attribute__((address_space(1))) void*)(gp),               \
      (__attribute__((address_space(3))) void*)(lp), 16, 0, 0)

__device__ __forceinline__ u16 f2bf(float f) {
  union { float f; uint32_t u; } v;
  v.f = f;
  uint32_t u = v.u;
  uint32_t r = u + 0x7fffu + ((u >> 16) & 1u);
  return (u16)(r >> 16);
}

__device__ __forceinline__ float bf2f(u16 b) {
  union { uint32_t u; float f; } v;
  v.u = ((uint32_t)b) << 16;
  return v.f;
}

// Stage a 128-row x 64-col f32 tile (row stride ld) into swizzled bf16 LDS.
// LDS layout: row*64 + (slot ^ (row&7))*8, slot = k/8 (8 slots of 8 bf16 = 16B).
__device__ __forceinline__ void stage_tile(u16* lds, const float* src, int ld, int tid) {
#pragma unroll
  for (int q = 0; q < 4; ++q) {
    int slot_id = tid + (q << 8);
    int row = slot_id >> 3;
    int sl = slot_id & 7;
    const float* p = src + (size_t)row * ld + (sl << 3);
    float4 x0 = *(const float4*)(p);
    float4 x1 = *(const float4*)(p + 4);
    ushortx8 o;
    o[0] = f2bf(x0.x); o[1] = f2bf(x0.y); o[2] = f2bf(x0.z); o[3] = f2bf(x0.w);
    o[4] = f2bf(x1.x); o[5] = f2bf(x1.y); o[6] = f2bf(x1.z); o[7] = f2bf(x1.w);
    *(ushortx8*)(&lds[(row << 6) + (((sl ^ (row & 7)) << 3))]) = o;
  }
}

// ---------------- conv: f32 matrix -> tiled pre-swizzled bf16 ----------------
__global__ __launch_bounds__(256) void conv_tile_kernel(const float* __restrict__ src,
                                                        int ld, int ntile_k,
                                                        u16* __restrict__ dst) {
  int bid = blockIdx.x;
  int rt = bid / ntile_k;        // row-tile (128 rows)
  int kt = bid - rt * ntile_k;   // k-tile (64 cols)
  const float* s0 = src + (size_t)rt * 128 * ld + kt * 64;
  u16* d0 = dst + (size_t)bid * 8192;
  int tid = threadIdx.x;
#pragma unroll
  for (int q = 0; q < 4; ++q) {
    int slot_id = tid + (q << 8);
    int row = slot_id >> 3;
    int sl = slot_id & 7;
    const float* p = s0 + (size_t)row * ld + (sl << 3);
    float4 x0 = *(const float4*)(p);
    float4 x1 = *(const float4*)(p + 4);
    ushortx8 o;
    o[0] = f2bf(x0.x); o[1] = f2bf(x0.y); o[2] = f2bf(x0.z); o[3] = f2bf(x0.w);
    o[4] = f2bf(x1.x); o[5] = f2bf(x1.y); o[6] = f2bf(x1.z); o[7] = f2bf(x1.w);
    *(ushortx8*)(&d0[(row << 6) + (((sl ^ (row & 7)) << 3))]) = o;
  }
}

// ---------------- K1: sentence mean pooling from tiled bf16 hbf ----------------
__global__ __launch_bounds__(256) void pool_bf_kernel(const u16* __restrict__ hbf,
                                                      const int* __restrict__ bounds,
                                                      float* __restrict__ sent) {
  int bs = blockIdx.x;           // b*64 + s
  int b = bs >> 6;
  int start = bounds[bs * 2];
  int end = bounds[bs * 2 + 1];
  int lo = max(start, 0), hi = min(end, TT);
  int cnt = max(hi - lo, 0);
  float inv = 1.0f / (float)max(cnt, 1);
  int tid = threadIdx.x;
  int sg = tid >> 1;             // 0..127 -> cols sg*8 .. sg*8+7
  int half = tid & 1;
  int kt = sg >> 3, slot = sg & 7;
  float a[8] = {};
  for (int t = lo + half; t < hi; t += 2) {
    int grow = b * TT + t;
    int rt = grow >> 7, r = grow & 127;
    const u16* tile = hbf + ((size_t)rt * 16 + kt) * 8192;
    ushortx8 v = *(const ushortx8*)(&tile[(r << 6) + ((slot ^ (r & 7)) << 3)]);
#pragma unroll
    for (int j = 0; j < 8; ++j) a[j] += bf2f(v[j]);
  }
#pragma unroll
  for (int j = 0; j < 8; ++j) a[j] += __shfl_xor(a[j], 1);
  if (half == 0) {
    float* d = sent + (size_t)bs * HH + sg * 8;
#pragma unroll
    for (int j = 0; j < 8; ++j) d[j] = a[j] * inv;
  }
}

// ---------------- setup: bias-init qkv/att/cbuf + sid, one grid-stride kernel ----------------
__global__ __launch_bounds__(256) void setup_misc(const float* __restrict__ ipb,
                                                  const float* __restrict__ outb,
                                                  const float* __restrict__ b1,
                                                  const int* __restrict__ bounds,
                                                  float* __restrict__ qkv,
                                                  float* __restrict__ att,
                                                  float* __restrict__ cbuf,
                                                  int* __restrict__ sid) {
  int idx = blockIdx.x * 256 + threadIdx.x;
  const int STR = 2048 * 256;
  for (int i = idx; i < 512 * 3072; i += STR) qkv[i] = ipb[i % 3072];
  for (int i = idx; i < 512 * 1024; i += STR) att[i] = outb[i & 1023];
  for (int i = idx; i < 512 * 1024; i += STR) cbuf[i] = b1[i & 1023];
  if (idx < BB * TT) {
    int b = idx >> 12, t = idx & (TT - 1);
    int r = -1;
    for (int s = 0; s < SS; ++s) {
      int st = bounds[(b * SS + s) * 2], en = bounds[(b * SS + s) * 2 + 1];
      if (t >= st && t < en) { r = s; break; }
    }
    sid[idx] = r;
  }
}

// ---------------- C += A @ B^T via atomics, K-split over blockIdx.z ----------------
__global__ __launch_bounds__(256) void gemm_bt_atomic(const float* __restrict__ A, int lda,
                                                      const float* __restrict__ Bm, int ldb,
                                                      float* __restrict__ C, int ldc,
                                                      int kper) {
  __shared__ u16 As[128 * 64];
  __shared__ u16 Bs[128 * 64];
  int tid = threadIdx.x;
  int m0 = blockIdx.x * 128, n0 = blockIdx.y * 128;
  int kbeg = blockIdx.z * kper;
  f32x4 acc[4][4] = {};

  for (int k0 = kbeg; k0 < kbeg + kper; k0 += 64) {
    __syncthreads();
    stage_tile(As, A + (size_t)m0 * lda + k0, lda, tid);
    stage_tile(Bs, Bm + (size_t)n0 * ldb + k0, ldb, tid);
    __syncthreads();
    int lane = tid & 63, wid = tid >> 6;
    int wm = wid >> 1, wn = wid & 1;
    int lr = lane & 15, lg = lane >> 4;
#pragma unroll
    for (int kk = 0; kk < 2; ++kk) {
      short8 af[4], bfr[4];
#pragma unroll
      for (int i = 0; i < 4; ++i) {
        int arow = wm * 64 + i * 16 + lr;
        int aslot = (kk * 4 + lg) ^ (arow & 7);
        af[i] = *(const short8*)(&As[(arow << 6) + (aslot << 3)]);
        int brow = wn * 64 + i * 16 + lr;
        int bslot = (kk * 4 + lg) ^ (brow & 7);
        bfr[i] = *(const short8*)(&Bs[(brow << 6) + (bslot << 3)]);
      }
#pragma unroll
      for (int i = 0; i < 4; ++i)
#pragma unroll
        for (int j = 0; j < 4; ++j)
          acc[i][j] = __builtin_amdgcn_mfma_f32_16x16x32_bf16(af[i], bfr[j], acc[i][j], 0, 0, 0);
    }
  }

  int lane = tid & 63, wid = tid >> 6;
  int wm = wid >> 1, wn = wid & 1;
  int lr = lane & 15, lg = lane >> 4;
#pragma unroll
  for (int i = 0; i < 4; ++i)
#pragma unroll
    for (int j = 0; j < 4; ++j)
#pragma unroll
      for (int r = 0; r < 4; ++r) {
        int row = m0 + wm * 64 + i * 16 + lg * 4 + r;
        int col = n0 + wn * 64 + j * 16 + lr;
        atomicAdd(&C[(size_t)row * ldc + col], acc[i][j][r]);
      }
}

// ---------------- K4: attention over S=64 per (b, head) ----------------
__global__ __launch_bounds__(256) void attn_kernel(const float* __restrict__ qkv,
                                                   float* __restrict__ ctx) {
  int bh = blockIdx.x;
  int b = bh >> 4, nh = bh & 15;
  __shared__ float q[64][64], k[64][64], v[64][64], s[64][64];
  int tid = threadIdx.x;
  const float* base = qkv + (size_t)b * SS * 3072 + nh * 64;
  for (int e = tid; e < 4096; e += 256) {
    int i = e >> 6, d = e & 63;
    q[i][d] = base[(size_t)i * 3072 + d];
    k[i][d] = base[(size_t)i * 3072 + 1024 + d];
    v[i][d] = base[(size_t)i * 3072 + 2048 + d];
  }
  __syncthreads();
  for (int e = tid; e < 4096; e += 256) {
    int i = e >> 6, j = e & 63;
    float acc = 0.f;
#pragma unroll 8
    for (int d = 0; d < 64; ++d) acc += q[i][d] * k[j][d];
    s[i][j] = acc * 0.125f;  // 1/sqrt(64)
  }
  __syncthreads();
  {
    int r = tid >> 2, sub = tid & 3;
    int j0 = sub * 16;
    float m = -1e30f;
#pragma unroll
    for (int j = 0; j < 16; ++j) m = fmaxf(m, s[r][j0 + j]);
    m = fmaxf(m, __shfl_xor(m, 1));
    m = fmaxf(m, __shfl_xor(m, 2));
    float sum = 0.f;
#pragma unroll
    for (int j = 0; j < 16; ++j) {
      float e_ = __expf(s[r][j0 + j] - m);
      s[r][j0 + j] = e_;
      sum += e_;
    }
    sum += __shfl_xor(sum, 1);
    sum += __shfl_xor(sum, 2);
    float inv = 1.0f / sum;
#pragma unroll
    for (int j = 0; j < 16; ++j) s[r][j0 + j] *= inv;
  }
  __syncthreads();
  for (int e = tid; e < 4096; e += 256) {
    int i = e >> 6, d = e & 63;
    float acc = 0.f;
#pragma unroll 8
    for (int j = 0; j < 64; ++j) acc += s[i][j] * v[j][d];
    ctx[((size_t)b * SS + i) * HH + nh * 64 + d] = acc;
  }
}

// ---------------- K7: partial score, 512 threads / 8 waves (2m x 4n) ----------------
// Same round-5 two-barrier single-buffer loop and XCD-grouped mapping; wave
// geometry changed to 8 waves of 64x32 so 2-3 blocks/CU = 16-24 waves/CU hide
// the stage->barrier->compute latency chain via TLP (round 5-7 showed all sync
// restructures neutral at ~7 waves/CU; this attacks occupancy instead).
__global__ __launch_bounds__(512, 6) void score_partial(const u16* __restrict__ hbf,
                                                        const u16* __restrict__ wbf,
                                                        const float* __restrict__ cbuf,
                                                        const float* __restrict__ w2,
                                                        const int* __restrict__ sid_arr,
                                                        float* __restrict__ score_part) {
  __shared__ u16 As[8192];
  __shared__ u16 Bs[8192];
  __shared__ float w2_lds[128];
  __shared__ int sid_lds[128];
  __shared__ float red[128];

  int tid = threadIdx.x;
  int bid = blockIdx.x;
  int x = bid & 7;
  int g = bid >> 3;
  int mt = x * 32 + (g >> 3);
  int c = g & 7;
  int n0 = c * 128;
  size_t g0 = (size_t)mt * 128;  // global token row
  int b = (int)(g0 >> 12);       // / T
  const u16* asrc = hbf + (size_t)mt * 16 * 8192;
  const u16* bsrc = wbf + (size_t)c * 16 * 8192;

  if (tid < 128) {
    w2_lds[tid] = w2[n0 + tid];
    sid_lds[tid] = sid_arr[g0 + tid];
    red[tid] = 0.f;
  }

  int lane = tid & 63, wid = tid >> 6;  // wid 0..7
  int wm = wid >> 2, wn = wid & 3;      // 2 x 4 wave grid, each 64x32
  int lr = lane & 15, lg = lane >> 4;

  f32x4 acc[4][2] = {};
  for (int kt = 0; kt < 16; ++kt) {
    __syncthreads();  // previous iteration's LDS reads complete
    const u16* at = asrc + kt * 8192;
    const u16* bt = bsrc + kt * 8192;
#pragma unroll
    for (int q = 0; q < 2; ++q) {
      int base = q * 4096 + wid * 512;  // wave-uniform u16 base
      GLOAD16(at + base + lane * 8, &As[base]);
      GLOAD16(bt + base + lane * 8, &Bs[base]);
    }
    __syncthreads();  // compiler drains vmcnt(0) before barrier -> tile ready
#pragma unroll
    for (int kk = 0; kk < 2; ++kk) {
      short8 af[4], bfr[2];
#pragma unroll
      for (int i = 0; i < 4; ++i) {
        int arow = wm * 64 + i * 16 + lr;
        int aslot = (kk * 4 + lg) ^ (arow & 7);
        af[i] = *(const short8*)(&As[(arow << 6) + (aslot << 3)]);
      }
#pragma unroll
      for (int j = 0; j < 2; ++j) {
        int brow = wn * 32 + j * 16 + lr;
        int bslot = (kk * 4 + lg) ^ (brow & 7);
        bfr[j] = *(const short8*)(&Bs[(brow << 6) + (bslot << 3)]);
      }
#pragma unroll
      for (int i = 0; i < 4; ++i)
#pragma unroll
        for (int j = 0; j < 2; ++j)
          acc[i][j] = __builtin_amdgcn_mfma_f32_16x16x32_bf16(af[i], bfr[j], acc[i][j], 0, 0, 0);
    }
  }

  // score epilogue: sp = sum_j w2[j] * relu(u + c[sid, j]) over this wave's 32 cols
  float sp[4][4];
#pragma unroll
  for (int i = 0; i < 4; ++i) {
#pragma unroll
    for (int r = 0; r < 4; ++r) {
      int rowl = wm * 64 + i * 16 + lg * 4 + r;
      int s = sid_lds[rowl];
      int sc = s < 0 ? 0 : s;
      const float* crow = cbuf + ((size_t)b * SS + sc) * HH + n0;
      float accs = 0.f;
#pragma unroll
      for (int j = 0; j < 2; ++j) {
        int coll = wn * 32 + j * 16 + lr;
        float t = acc[i][j][r] + crow[coll];
        if (t > 0.f) accs += t * w2_lds[coll];
      }
      sp[i][r] = accs;
    }
  }

  // reduce across the 16 lanes of each lane-group
#pragma unroll
  for (int i = 0; i < 4; ++i)
#pragma unroll
    for (int r = 0; r < 4; ++r) {
      float v = sp[i][r];
      v += __shfl_xor(v, 1);
      v += __shfl_xor(v, 2);
      v += __shfl_xor(v, 4);
      v += __shfl_xor(v, 8);
      sp[i][r] = v;
    }
  if (lr == 0) {
#pragma unroll
    for (int i = 0; i < 4; ++i)
#pragma unroll
      for (int r = 0; r < 4; ++r)
        atomicAdd(&red[wm * 64 + i * 16 + lg * 4 + r], sp[i][r]);
  }
  __syncthreads();
  if (tid < 128) score_part[(size_t)c * (BB * TT) + g0 + tid] = red[tid];
}

// ---------------- K9: out = h * (1 + covered*(sum_c spart + b2)) ----------------
__global__ __launch_bounds__(256) void scale_kernel(const float* __restrict__ h,
                                                    const float* __restrict__ score_part,
                                                    const float* __restrict__ b2,
                                                    const int* __restrict__ sid_arr,
                                                    float* __restrict__ out) {
  __shared__ float fac[16];
  int tid = threadIdx.x;
  int r0 = blockIdx.x * 16;
  if (tid < 16) {
    int t = r0 + tid;
    float s = b2[0];
#pragma unroll
    for (int c = 0; c < 8; ++c) s += score_part[(size_t)c * (BB * TT) + t];
    fac[tid] = (sid_arr[t] >= 0) ? (1.0f + s) : 1.0f;
  }
  __syncthreads();
  const float4* h4 = (const float4*)h + (size_t)r0 * 256;
  float4* o4 = (float4*)out + (size_t)r0 * 256;
  for (int e = tid; e < 16 * 256; e += 256) {
    float f = fac[e >> 8];
    float4 v = h4[e];
    v.x *= f; v.y *= f; v.z *= f; v.w *= f;
    o4[e] = v;
  }
}

extern "C" void kernel_launch(void* const* d_in, const int* in_sizes, int n_in,
                              void* d_out, int out_size, void* d_ws, size_t ws_size,
                              hipStream_t stream) {
  const float* h        = (const float*)d_in[0];
  const int*   bounds   = (const int*)d_in[1];
  const float* in_proj_w = (const float*)d_in[2];
  const float* in_proj_b = (const float*)d_in[3];
  const float* out_w    = (const float*)d_in[4];
  const float* out_b    = (const float*)d_in[5];
  const float* w1       = (const float*)d_in[6];
  const float* b1       = (const float*)d_in[7];
  const float* w2       = (const float*)d_in[8];
  const float* b2       = (const float*)d_in[9];
  float* out = (float*)d_out;

  char* ws = (char*)d_ws;
  float* sent  = (float*)(ws);                        // 2 MB
  float* qkv   = (float*)(ws + (2ull << 20));         // 6 MB
  float* ctx   = (float*)(ws + (8ull << 20));         // 2 MB
  float* att   = (float*)(ws + (10ull << 20));        // 2 MB
  float* cbuf  = (float*)(ws + (12ull << 20));        // 2 MB
  int*   sid   = (int*)(ws + (14ull << 20));          // 128 KB
  float* spart = (float*)(ws + (15ull << 20));        // 1 MB
  u16*   hbf   = (u16*)(ws + (16ull << 20));          // 64 MB
  u16*   wbf   = (u16*)(ws + (80ull << 20));          // 2 MB

  // pre-convert operands of the big GEMM to tiled/swizzled bf16
  conv_tile_kernel<<<256 * 16, 256, 0, stream>>>(h, HH, 16, hbf);
  conv_tile_kernel<<<8 * 16, 256, 0, stream>>>(w1, 2 * HH, 16, wbf);  // w1a: k<1024

  pool_bf_kernel<<<BB * SS, 256, 0, stream>>>(hbf, bounds, sent);
  setup_misc<<<2048, 256, 0, stream>>>(in_proj_b, out_b, b1, bounds, qkv, att, cbuf, sid);

  // qkv = sent @ in_proj_w^T + in_proj_b   (512 x 3072, K=1024), K-split x4
  gemm_bt_atomic<<<dim3(4, 24, 4), 256, 0, stream>>>(sent, HH, in_proj_w, HH, qkv, 3 * HH, 256);
  attn_kernel<<<BB * NHH, 256, 0, stream>>>(qkv, ctx);
  // attended = ctx @ out_w^T + out_b       (512 x 1024, K=1024), K-split x4
  gemm_bt_atomic<<<dim3(4, 8, 4), 256, 0, stream>>>(ctx, HH, out_w, HH, att, HH, 256);
  // c = attended @ w1b^T + b1              (512 x 1024, K=1024), w1b = w1[:, H:]
  gemm_bt_atomic<<<dim3(4, 8, 4), 256, 0, stream>>>(att, HH, w1 + HH, 2 * HH, cbuf, HH, 256);

  // big GEMM partial scores: 2048 blocks, XCD-grouped, 8-wave blocks
  score_partial<<<2048, 512, 0, stream>>>(hbf, wbf, cbuf, w2, sid, spart);
  scale_kernel<<<2048, 256, 0, stream>>>(h, spart, b2, sid, out);
}